// Round 4
// baseline (933.813 us; speedup 1.0000x reference)
//
#include <hip/hip_runtime.h>
#include <cstdint>

#define VOCAB 500000
#define STEPS 64
#define EPSF 1e-8f

__device__ __forceinline__ float sigm(float x) { return 1.f / (1.f + expf(-x)); }
__device__ __forceinline__ float dot4(float4 a, float4 b) {
    return a.x * b.x + a.y * b.y + a.z * b.z + a.w * b.w;
}
__device__ __forceinline__ unsigned long long ullmax(unsigned long long a, unsigned long long b) {
    return a > b ? a : b;
}
// order-preserving float->uint32 map (monotone increasing)
__device__ __forceinline__ unsigned fmap(float f) {
    unsigned u = __float_as_uint(f);
    return (u & 0x80000000u) ? ~u : (u | 0x80000000u);
}

// Pin a float4's lanes into VGPRs (blocks rematerialization of the defining loads).
#define PIN4(v) asm volatile("" : "+v"(v.x), "+v"(v.y), "+v"(v.z), "+v"(v.w))

// ---------------- Kernel A: 64-step LSTM recurrence (single block, 1024 threads) ----------------
// R1-R3 evidence: allocator remats large plain-C persistent weight arrays from L2 in-loop
// (R1 6.06us/step, R3 5.0us/step @ VGPR=64); PIN with demand>budget spills to scratch
// (R2 9.3us/step). v4 splits the 4 gates across storage classes so pinned demand fits:
//   gates i,f : 64 VGPR, PIN4'd (demand 64+~40 working < 128 budget @ 1024 thr)
//   gate  g   : streamed from global (L2) every step - explicit, predictable
//   gate  o   : LDS column-major [j4][t], linear conflict-free ds_read_b128
// Thread t: cell q=t&127, column-group g=t>>7 (32 of the 256 active cols [x;h]).
__global__ void __launch_bounds__(1024) lstm_kernel(
    const float* __restrict__ inp, const float* __restrict__ embed,
    const float* __restrict__ w_ih, const float* __restrict__ w_hh,
    const float* __restrict__ b_ih, const float* __restrict__ b_hh,
    float* __restrict__ out_cs,                 // d_out[0 .. 64*128)
    unsigned long long* __restrict__ slots)     // ws: 64 argmax slots
{
    __shared__ float4 wlds4[8 * 1024];   // 128 KB: o-gate weights, column-major [j4][t]
    __shared__ float4 part4[8 * 128];    // 16 KB: per-(group, cell) gate partials
    __shared__ float vv[256];            // [x(128) ; h(128)]
    __shared__ float kvlds[512];         // per-row constant: b_ih+b_hh+w_ih[:,128:256].inp

    const int t = threadIdx.x;
    const int q = t & 127;               // cell index
    const int g = t >> 7;                // column group (0..7), wave-uniform

    if (t < STEPS) slots[t] = 0ull;      // init argmax slots (vocab kernel is stream-ordered after)

    const float4* wih4 = (const float4*)w_ih;   // row stride 64 float4
    const float4* whh4 = (const float4*)w_hh;   // row stride 32 float4

    // Register weights for gates i (rows q) and f (rows q+128), cols [32g, 32g+32).
    float4 wr0[8], wr1[8];
    {
        const float4* s0 = (g < 4) ? (wih4 + (size_t)q * 64 + g * 8)
                                   : (whh4 + (size_t)q * 32 + (g - 4) * 8);
#pragma unroll
        for (int j4 = 0; j4 < 8; ++j4) wr0[j4] = s0[j4];
        const int r1 = q + 128;
        const float4* s1 = (g < 4) ? (wih4 + (size_t)r1 * 64 + g * 8)
                                   : (whh4 + (size_t)r1 * 32 + (g - 4) * 8);
#pragma unroll
        for (int j4 = 0; j4 < 8; ++j4) wr1[j4] = s1[j4];
    }
#pragma unroll
    for (int j4 = 0; j4 < 8; ++j4) PIN4(wr0[j4]);
#pragma unroll
    for (int j4 = 0; j4 < 8; ++j4) PIN4(wr1[j4]);

    // o-gate (rows q+384) weights -> LDS column-major
    {
        const int r3 = q + 384;
        const float4* s3 = (g < 4) ? (wih4 + (size_t)r3 * 64 + g * 8)
                                   : (whh4 + (size_t)r3 * 32 + (g - 4) * 8);
#pragma unroll
        for (int j4 = 0; j4 < 8; ++j4) wlds4[j4 * 1024 + t] = s3[j4];
    }

    // g-gate (rows q+256) stream pointer: re-read from L2 every step
    const float4* wgp = (g < 4) ? (wih4 + (size_t)(q + 256) * 64 + g * 8)
                                : (whh4 + (size_t)(q + 256) * 32 + (g - 4) * 8);

    // kv[r] = b_ih[r] + b_hh[r] + w_ih[r][128:256] . inp  (constant across steps)
    if (t < 512) {
        const float4* wib = wih4 + (size_t)t * 64 + 32;
        const float4* inp4 = (const float4*)inp;
        float k0 = 0.f, k1 = 0.f;
#pragma unroll 4
        for (int j = 0; j < 32; j += 2) {
            k0 += dot4(wib[j], inp4[j]);
            k1 += dot4(wib[j + 1], inp4[j + 1]);
        }
        kvlds[t] = b_ih[t] + b_hh[t] + k0 + k1;
    }

    if (t < 128) { vv[t] = embed[t]; vv[128 + t] = 0.f; }  // x0 = embed[0], h0 = 0
    float creg = 0.f;
    __syncthreads();

    const float4* vv4 = (const float4*)vv;
    const int vb = g * 8;
    for (int step = 0; step < STEPS; ++step) {
        float ax = 0.f, ay = 0.f, az = 0.f, aw = 0.f;
#pragma unroll
        for (int j4 = 0; j4 < 8; ++j4) {
            float4 v  = vv4[vb + j4];               // LDS broadcast (wave-uniform addr)
            float4 w2 = wgp[j4];                    // g-gate: global stream (L2-resident)
            float4 w3 = wlds4[j4 * 1024 + t];       // o-gate: LDS linear, conflict-free
            ax += dot4(wr0[j4], v);
            ay += dot4(wr1[j4], v);
            az += dot4(w2, v);
            aw += dot4(w3, v);
        }
        part4[g * 128 + q] = make_float4(ax, ay, az, aw);
        __syncthreads();
        if (t < 128) {
            float4 s = part4[t];                    // g = 0
#pragma unroll
            for (int g2 = 1; g2 < 8; ++g2) {
                float4 p = part4[g2 * 128 + t];
                s.x += p.x; s.y += p.y; s.z += p.z; s.w += p.w;
            }
            float ig = sigm(s.x + kvlds[t]);
            float fg = sigm(s.y + kvlds[128 + t]);
            float gg = tanhf(s.z + kvlds[256 + t]);
            float og = sigm(s.w + kvlds[384 + t]);
            float cn = fg * creg + ig * gg;
            float hn = og * tanhf(cn);
            creg = cn;
            vv[t] = cn;            // next x = c_new
            vv[128 + t] = hn;      // next h
            out_cs[step * 128 + t] = cn;
        }
        __syncthreads();
    }
}

// ---------------- Kernel B: one pass over embed, 64 dots/row + norm + argmax ----------------
// 256 threads, 256 rows/block (4 tiles of 64). Thread = (tx=tid&15 -> t in {tx,tx+16,tx+32,tx+48},
// ry=tid>>4 -> rows {ry,ry+16,ry+32,ry+48}). ssq computed at staging time (per-(row,j4) partials),
// inner loop is pure acc FMAs: 8 b128 LDS reads + 16 dot4 per j4.
__global__ __launch_bounds__(256)
__attribute__((amdgpu_waves_per_eu(2, 2)))
void vocab_kernel(
    const float* __restrict__ embed,
    const float* __restrict__ cs,               // d_out[0..8192): [64][128] c vectors
    unsigned long long* __restrict__ slots)
{
    __shared__ float4 c_lds[64 * 32];   // 32 KB, swizzled [t][j4 ^ (t&31)]
    __shared__ float4 e_lds[64 * 32];   // 32 KB, swizzled; reused as u64 reduction scratch
    __shared__ float ssq_part[64 * 32]; // 8 KB: per-(row,j4) |e4|^2 partials, written at staging

    const int tid = threadIdx.x;
    const int tx = tid & 15, ry = tid >> 4;

    // stage c matrix once (swizzled)
    const float4* cs4 = (const float4*)cs;
#pragma unroll 2
    for (int k = 0; k < 8; ++k) {
        int f = tid + k * 256;
        int row = f >> 5, j4 = f & 31;
        c_lds[row * 32 + (j4 ^ (row & 31))] = cs4[f];
    }

    unsigned long long running = 0ull;   // tid<64: best key for t = tid
    const long long blockbase = (long long)blockIdx.x * 256;
    const float4* embed4 = (const float4*)embed;

    int Pe[4], Pc[4];
#pragma unroll
    for (int rr = 0; rr < 4; ++rr) { int row = ry + 16 * rr; Pe[rr] = row * 32 + (row & 31); }
#pragma unroll
    for (int tt = 0; tt < 4; ++tt) { int t = tx + 16 * tt; Pc[tt] = t * 32 + (t & 31); }

    for (int tile = 0; tile < 4; ++tile) {
        const long long rowbase = blockbase + tile * 64;
        __syncthreads();   // prev reduction reads done before restaging e_lds / ssq_part
#pragma unroll 2
        for (int k = 0; k < 8; ++k) {
            int f = tid + k * 256;
            int row = f >> 5, j4 = f & 31;
            long long grow = rowbase + row;
            float4 val = make_float4(0.f, 0.f, 0.f, 0.f);
            if (grow < VOCAB) val = embed4[grow * 32 + j4];
            e_lds[row * 32 + (j4 ^ (row & 31))] = val;
            ssq_part[row * 32 + j4] = dot4(val, val);
        }
        __syncthreads();

        float acc[4][4];
#pragma unroll
        for (int rr = 0; rr < 4; ++rr)
#pragma unroll
            for (int tt = 0; tt < 4; ++tt) acc[rr][tt] = 0.f;

#pragma unroll 2
        for (int j4 = 0; j4 < 32; ++j4) {
            float4 c0 = c_lds[Pc[0] ^ j4];
            float4 c1 = c_lds[Pc[1] ^ j4];
            float4 c2 = c_lds[Pc[2] ^ j4];
            float4 c3 = c_lds[Pc[3] ^ j4];
#pragma unroll
            for (int rr = 0; rr < 4; ++rr) {
                float4 e = e_lds[Pe[rr] ^ j4];
                acc[rr][0] += dot4(e, c0);
                acc[rr][1] += dot4(e, c1);
                acc[rr][2] += dot4(e, c2);
                acc[rr][3] += dot4(e, c3);
            }
        }

        // per-row inv-norm from staged partials (broadcast reads, once per tile)
        float inv[4];
        long long grows[4];
#pragma unroll
        for (int rr = 0; rr < 4; ++rr) {
            int row = ry + 16 * rr;
            float s0 = 0.f, s1 = 0.f;
#pragma unroll 4
            for (int j = 0; j < 32; j += 2) {
                s0 += ssq_part[row * 32 + j];
                s1 += ssq_part[row * 32 + j + 1];
            }
            inv[rr] = 1.f / fmaxf(sqrtf(s0 + s1), EPSF);
            grows[rr] = rowbase + row;
        }
        __syncthreads();   // all e_lds reads done; safe to reuse as scratch

        unsigned long long* red = (unsigned long long*)e_lds;  // [tt*256 + tx*16 + ry]
#pragma unroll
        for (int tt = 0; tt < 4; ++tt) {
            unsigned long long k = 0ull;
#pragma unroll
            for (int rr = 0; rr < 4; ++rr) {
                if (grows[rr] < VOCAB) {
                    float q = acc[rr][tt] * inv[rr];
                    unsigned long long key = ((unsigned long long)fmap(q) << 32)
                                           | (unsigned)(0x7FFFFFFF - (int)grows[rr]);
                    k = ullmax(k, key);
                }
            }
            red[tt * 256 + tx * 16 + ry] = k;
        }
        __syncthreads();

        if (tid < 64) {
            int t = tid, ttx = t & 15, ttt = t >> 4;
#pragma unroll
            for (int r2 = 0; r2 < 16; ++r2)
                running = ullmax(running, red[ttt * 256 + ttx * 16 + r2]);
        }
    }

    if (tid < 64) atomicMax(&slots[tid], running);
}

// ---------------- Kernel C: decode argmax slots to float indices ----------------
__global__ void finalize_kernel(const unsigned long long* __restrict__ slots,
                                float* __restrict__ out_dec)
{
    int t = threadIdx.x;
    if (t < STEPS) {
        unsigned idx = 0x7FFFFFFFu - (unsigned)(slots[t] & 0xFFFFFFFFu);
        out_dec[t] = (float)idx;
    }
}

extern "C" void kernel_launch(void* const* d_in, const int* in_sizes, int n_in,
                              void* d_out, int out_size, void* d_ws, size_t ws_size,
                              hipStream_t stream) {
    (void)in_sizes; (void)n_in; (void)out_size; (void)ws_size;
    const float* inp   = (const float*)d_in[0];
    const float* embed = (const float*)d_in[1];
    const float* w_ih  = (const float*)d_in[2];
    const float* w_hh  = (const float*)d_in[3];
    const float* b_ih  = (const float*)d_in[4];
    const float* b_hh  = (const float*)d_in[5];
    float* out = (float*)d_out;
    unsigned long long* slots = (unsigned long long*)d_ws;

    hipLaunchKernelGGL(lstm_kernel, dim3(1), dim3(1024), 0, stream,
                       inp, embed, w_ih, w_hh, b_ih, b_hh, out, slots);
    const int nblocks = (VOCAB + 255) / 256;   // 1954
    hipLaunchKernelGGL(vocab_kernel, dim3(nblocks), dim3(256), 0, stream,
                       embed, out, slots);
    hipLaunchKernelGGL(finalize_kernel, dim3(1), dim3(64), 0, stream,
                       slots, out + STEPS * 128);
}

// Round 5
// 680.089 us; speedup vs baseline: 1.3731x; 1.3731x over previous
//
#include <hip/hip_runtime.h>
#include <cstdint>

#define VOCAB 500000
#define STEPS 64
#define EPSF 1e-8f
#define NBLK 4

// ws layout: [0,512): argmax slots (u64[64]); [1024,1280): flags (u32[STEPS]);
// [4096, 4096+STEPS*NBLK*512*4): per-step per-block gate partials (step-indexed => no reuse races)
#define WS_FLAGS_OFF 1024
#define WS_PARTS_OFF 4096
#define WS_NEEDED (WS_PARTS_OFF + (size_t)STEPS * NBLK * 512 * 4)

__device__ __forceinline__ float sigm(float x) { return 1.f / (1.f + expf(-x)); }
__device__ __forceinline__ float dot4(float4 a, float4 b) {
    return a.x * b.x + a.y * b.y + a.z * b.z + a.w * b.w;
}
__device__ __forceinline__ unsigned long long ullmax(unsigned long long a, unsigned long long b) {
    return a > b ? a : b;
}
// order-preserving float->uint32 map (monotone increasing)
__device__ __forceinline__ unsigned fmap(float f) {
    unsigned u = __float_as_uint(f);
    return (u & 0x80000000u) ? ~u : (u | 0x80000000u);
}

// Pin a float4's lanes into VGPRs (blocks rematerialization of the defining loads).
#define PIN4(v) asm volatile("" : "+v"(v.x), "+v"(v.y), "+v"(v.z), "+v"(v.w))

// ---------------- Kernel A (v5): 4-block column-partitioned LSTM recurrence ----------------
// R1-R4 evidence: allocator gives this kernel 64 VGPRs no matter what attributes say; 512 KB
// of live weights can never be resident on one CU. v5 partitions the 256 v-columns across
// 4 blocks: each block holds 512 rows x 64 cols = 128 KB of weights in REGISTERS
// (8 float4/thread = 32 VGPR, fits the observed 64-reg budget). Per step, blocks exchange
// 512-float partial sums through L3 with device-scope atomics (per-step flag; step-indexed
// partial buffers; identical summation order in all blocks keeps state bit-identical).
__global__ void __launch_bounds__(1024) lstm4_kernel(
    const float* __restrict__ inp, const float* __restrict__ embed,
    const float* __restrict__ w_ih, const float* __restrict__ w_hh,
    const float* __restrict__ b_ih, const float* __restrict__ b_hh,
    float* __restrict__ out_cs,                 // d_out[0 .. 64*128)
    void* __restrict__ ws)
{
    unsigned long long* slots = (unsigned long long*)ws;
    unsigned* flags = (unsigned*)((char*)ws + WS_FLAGS_OFF);
    float* parts = (float*)((char*)ws + WS_PARTS_OFF);

    __shared__ float vv[256];         // [x(128) ; h(128)] - replicated per block
    __shared__ float part_lds[1024];  // in-block partial reduce (2 col-halves)
    __shared__ float Glds[512];       // assembled gate pre-activations
    __shared__ float kvlds[512];      // b_ih+b_hh+w_ih[:,128:256].inp

    const int t = threadIdx.x;
    const int b = blockIdx.x;
    const int r = t & 511;            // gate row
    const int ch = t >> 9;            // column half within block's slice
    const int CF0 = b * 16 + ch * 8;  // this thread's column-float4 base in v (0..63)

    if (b == 0 && t < STEPS) slots[t] = 0ull;   // vocab kernel is stream-ordered after

    const float4* wih4 = (const float4*)w_ih;   // row stride 64 float4
    const float4* whh4 = (const float4*)w_hh;   // row stride 32 float4

    // 8 float4 of weights per thread, in registers (32 VGPR pinned; demand ~57 < 64 budget)
    float4 w[8];
#pragma unroll
    for (int j = 0; j < 8; ++j) {
        const int cf = CF0 + j;
        w[j] = (cf < 32) ? wih4[(size_t)r * 64 + cf]
                         : whh4[(size_t)r * 32 + (cf - 32)];
    }
#pragma unroll
    for (int j = 0; j < 8; ++j) PIN4(w[j]);

    // kv[r] = b_ih[r] + b_hh[r] + w_ih[r][128:256] . inp  (constant across steps)
    if (t < 512) {
        const float4* wib = wih4 + (size_t)t * 64 + 32;
        const float4* inp4 = (const float4*)inp;
        float k0 = 0.f, k1 = 0.f;
#pragma unroll 4
        for (int j = 0; j < 32; j += 2) {
            k0 += dot4(wib[j], inp4[j]);
            k1 += dot4(wib[j + 1], inp4[j + 1]);
        }
        kvlds[t] = b_ih[t] + b_hh[t] + k0 + k1;
    }
    if (t < 128) { vv[t] = embed[t]; vv[128 + t] = 0.f; }  // x0 = embed[0], h0 = 0
    float creg = 0.f;
    __syncthreads();

    const float4* vv4 = (const float4*)vv;
    for (int step = 0; step < STEPS; ++step) {
        // local matvec over this block's 16 column-float4s (registers + LDS broadcast)
        float a = 0.f;
#pragma unroll
        for (int j = 0; j < 8; ++j) a += dot4(w[j], vv4[CF0 + j]);
        part_lds[t] = a;
        __syncthreads();

        // in-block reduce of the 2 column halves; publish via agent-scope atomic store
        // (write-through: no L2 writeback fence needed; __syncthreads drains vmcnt)
        float myp = 0.f;
        if (t < 512) {
            myp = part_lds[t] + part_lds[512 + t];
            __hip_atomic_store(&parts[((size_t)step * NBLK + b) * 512 + t], myp,
                               __ATOMIC_RELAXED, __HIP_MEMORY_SCOPE_AGENT);
        }
        __syncthreads();

        if (t == 0) {
            __hip_atomic_fetch_add(&flags[step], 1u, __ATOMIC_RELEASE,
                                   __HIP_MEMORY_SCOPE_AGENT);
            while (__hip_atomic_load(&flags[step], __ATOMIC_ACQUIRE,
                                     __HIP_MEMORY_SCOPE_AGENT) < (unsigned)NBLK) {
                __builtin_amdgcn_s_sleep(1);
            }
        }
        __syncthreads();

        // assemble gates: identical summation order in all blocks -> bit-identical state
        if (t < 512) {
            float s = kvlds[t];
#pragma unroll
            for (int bb = 0; bb < NBLK; ++bb) {
                float p = (bb == b) ? myp
                        : __hip_atomic_load(&parts[((size_t)step * NBLK + bb) * 512 + t],
                                            __ATOMIC_RELAXED, __HIP_MEMORY_SCOPE_AGENT);
                s += p;
            }
            Glds[t] = s;
        }
        __syncthreads();

        if (t < 128) {
            float ig = sigm(Glds[t]);
            float fg = sigm(Glds[128 + t]);
            float gg = tanhf(Glds[256 + t]);
            float og = sigm(Glds[384 + t]);
            float cn = fg * creg + ig * gg;
            float hn = og * tanhf(cn);
            creg = cn;
            vv[t] = cn;            // next x = c_new
            vv[128 + t] = hn;      // next h
            if (b == 0) out_cs[step * 128 + t] = cn;
        }
        __syncthreads();
    }
}

// ---------------- Kernel A fallback (R3 version, 318us): used if ws too small ----------------
__global__ void __launch_bounds__(1024) lstm_kernel(
    const float* __restrict__ inp, const float* __restrict__ embed,
    const float* __restrict__ w_ih, const float* __restrict__ w_hh,
    const float* __restrict__ b_ih, const float* __restrict__ b_hh,
    float* __restrict__ out_cs,
    unsigned long long* __restrict__ slots)
{
    __shared__ float4 wlds4[8 * 1024];   // 128 KB: o-gate weights, column-major [j4][t]
    __shared__ float4 part4[8 * 128];    // 16 KB: per-(group, cell) gate partials
    __shared__ float vv[256];
    __shared__ float kvlds[512];

    const int t = threadIdx.x;
    const int q = t & 127;
    const int g = t >> 7;

    if (t < STEPS) slots[t] = 0ull;

    const float4* wih4 = (const float4*)w_ih;
    const float4* whh4 = (const float4*)w_hh;

    float4 wr[3][8];
#pragma unroll
    for (int k = 0; k < 3; ++k) {
        const int r = q + 128 * k;
        const float4* src = (g < 4) ? (wih4 + (size_t)r * 64 + g * 8)
                                    : (whh4 + (size_t)r * 32 + (g - 4) * 8);
#pragma unroll
        for (int j4 = 0; j4 < 8; ++j4) wr[k][j4] = src[j4];
    }
    {
        const int r = q + 384;
        const float4* src = (g < 4) ? (wih4 + (size_t)r * 64 + g * 8)
                                    : (whh4 + (size_t)r * 32 + (g - 4) * 8);
#pragma unroll
        for (int j4 = 0; j4 < 8; ++j4) wlds4[j4 * 1024 + t] = src[j4];
    }

    if (t < 512) {
        const float4* wib = wih4 + (size_t)t * 64 + 32;
        const float4* inp4 = (const float4*)inp;
        float k0 = 0.f, k1 = 0.f;
#pragma unroll 4
        for (int j = 0; j < 32; j += 2) {
            k0 += dot4(wib[j], inp4[j]);
            k1 += dot4(wib[j + 1], inp4[j + 1]);
        }
        kvlds[t] = b_ih[t] + b_hh[t] + k0 + k1;
    }

    if (t < 128) { vv[t] = embed[t]; vv[128 + t] = 0.f; }
    float creg = 0.f;
    __syncthreads();

    const float4* vv4 = (const float4*)vv;
    const int vb = g * 8;
    for (int step = 0; step < STEPS; ++step) {
        float ax = 0.f, ay = 0.f, az = 0.f, aw = 0.f;
#pragma unroll
        for (int j4 = 0; j4 < 8; ++j4) {
            float4 v  = vv4[vb + j4];
            float4 w3 = wlds4[j4 * 1024 + t];
            ax += dot4(wr[0][j4], v);
            ay += dot4(wr[1][j4], v);
            az += dot4(wr[2][j4], v);
            aw += dot4(w3, v);
        }
        part4[g * 128 + q] = make_float4(ax, ay, az, aw);
        __syncthreads();
        if (t < 128) {
            float4 s = part4[t];
#pragma unroll
            for (int g2 = 1; g2 < 8; ++g2) {
                float4 p = part4[g2 * 128 + t];
                s.x += p.x; s.y += p.y; s.z += p.z; s.w += p.w;
            }
            float ig = sigm(s.x + kvlds[t]);
            float fg = sigm(s.y + kvlds[128 + t]);
            float gg = tanhf(s.z + kvlds[256 + t]);
            float og = sigm(s.w + kvlds[384 + t]);
            float cn = fg * creg + ig * gg;
            float hn = og * tanhf(cn);
            creg = cn;
            vv[t] = cn;
            vv[128 + t] = hn;
            out_cs[step * 128 + t] = cn;
        }
        __syncthreads();
    }
}

// ---------------- Kernel B: one pass over embed, 64 dots/row + norm + argmax ----------------
__global__ __launch_bounds__(256)
__attribute__((amdgpu_waves_per_eu(2, 2)))
void vocab_kernel(
    const float* __restrict__ embed,
    const float* __restrict__ cs,               // d_out[0..8192): [64][128] c vectors
    unsigned long long* __restrict__ slots)
{
    __shared__ float4 c_lds[64 * 32];   // 32 KB, swizzled [t][j4 ^ (t&31)]
    __shared__ float4 e_lds[64 * 32];   // 32 KB, swizzled; reused as u64 reduction scratch
    __shared__ float ssq_part[64 * 32]; // 8 KB: per-(row,j4) |e4|^2 partials

    const int tid = threadIdx.x;
    const int tx = tid & 15, ry = tid >> 4;

    const float4* cs4 = (const float4*)cs;
#pragma unroll 2
    for (int k = 0; k < 8; ++k) {
        int f = tid + k * 256;
        int row = f >> 5, j4 = f & 31;
        c_lds[row * 32 + (j4 ^ (row & 31))] = cs4[f];
    }

    unsigned long long running = 0ull;
    const long long blockbase = (long long)blockIdx.x * 256;
    const float4* embed4 = (const float4*)embed;

    int Pe[4], Pc[4];
#pragma unroll
    for (int rr = 0; rr < 4; ++rr) { int row = ry + 16 * rr; Pe[rr] = row * 32 + (row & 31); }
#pragma unroll
    for (int tt = 0; tt < 4; ++tt) { int t = tx + 16 * tt; Pc[tt] = t * 32 + (t & 31); }

    for (int tile = 0; tile < 4; ++tile) {
        const long long rowbase = blockbase + tile * 64;
        __syncthreads();
#pragma unroll 2
        for (int k = 0; k < 8; ++k) {
            int f = tid + k * 256;
            int row = f >> 5, j4 = f & 31;
            long long grow = rowbase + row;
            float4 val = make_float4(0.f, 0.f, 0.f, 0.f);
            if (grow < VOCAB) val = embed4[grow * 32 + j4];
            e_lds[row * 32 + (j4 ^ (row & 31))] = val;
            ssq_part[row * 32 + j4] = dot4(val, val);
        }
        __syncthreads();

        float acc[4][4];
#pragma unroll
        for (int rr = 0; rr < 4; ++rr)
#pragma unroll
            for (int tt = 0; tt < 4; ++tt) acc[rr][tt] = 0.f;

#pragma unroll 2
        for (int j4 = 0; j4 < 32; ++j4) {
            float4 c0 = c_lds[Pc[0] ^ j4];
            float4 c1 = c_lds[Pc[1] ^ j4];
            float4 c2 = c_lds[Pc[2] ^ j4];
            float4 c3 = c_lds[Pc[3] ^ j4];
#pragma unroll
            for (int rr = 0; rr < 4; ++rr) {
                float4 e = e_lds[Pe[rr] ^ j4];
                acc[rr][0] += dot4(e, c0);
                acc[rr][1] += dot4(e, c1);
                acc[rr][2] += dot4(e, c2);
                acc[rr][3] += dot4(e, c3);
            }
        }

        float inv[4];
        long long grows[4];
#pragma unroll
        for (int rr = 0; rr < 4; ++rr) {
            int row = ry + 16 * rr;
            float s0 = 0.f, s1 = 0.f;
#pragma unroll 4
            for (int j = 0; j < 32; j += 2) {
                s0 += ssq_part[row * 32 + j];
                s1 += ssq_part[row * 32 + j + 1];
            }
            inv[rr] = 1.f / fmaxf(sqrtf(s0 + s1), EPSF);
            grows[rr] = rowbase + row;
        }
        __syncthreads();

        unsigned long long* red = (unsigned long long*)e_lds;
#pragma unroll
        for (int tt = 0; tt < 4; ++tt) {
            unsigned long long k = 0ull;
#pragma unroll
            for (int rr = 0; rr < 4; ++rr) {
                if (grows[rr] < VOCAB) {
                    float q = acc[rr][tt] * inv[rr];
                    unsigned long long key = ((unsigned long long)fmap(q) << 32)
                                           | (unsigned)(0x7FFFFFFF - (int)grows[rr]);
                    k = ullmax(k, key);
                }
            }
            red[tt * 256 + tx * 16 + ry] = k;
        }
        __syncthreads();

        if (tid < 64) {
            int t = tid, ttx = t & 15, ttt = t >> 4;
#pragma unroll
            for (int r2 = 0; r2 < 16; ++r2)
                running = ullmax(running, red[ttt * 256 + ttx * 16 + r2]);
        }
    }

    if (tid < 64) atomicMax(&slots[tid], running);
}

// ---------------- Kernel C: decode argmax slots to float indices ----------------
__global__ void finalize_kernel(const unsigned long long* __restrict__ slots,
                                float* __restrict__ out_dec)
{
    int t = threadIdx.x;
    if (t < STEPS) {
        unsigned idx = 0x7FFFFFFFu - (unsigned)(slots[t] & 0xFFFFFFFFu);
        out_dec[t] = (float)idx;
    }
}

extern "C" void kernel_launch(void* const* d_in, const int* in_sizes, int n_in,
                              void* d_out, int out_size, void* d_ws, size_t ws_size,
                              hipStream_t stream) {
    (void)in_sizes; (void)n_in; (void)out_size;
    const float* inp   = (const float*)d_in[0];
    const float* embed = (const float*)d_in[1];
    const float* w_ih  = (const float*)d_in[2];
    const float* w_hh  = (const float*)d_in[3];
    const float* b_ih  = (const float*)d_in[4];
    const float* b_hh  = (const float*)d_in[5];
    float* out = (float*)d_out;
    unsigned long long* slots = (unsigned long long*)d_ws;

    if (ws_size >= WS_NEEDED) {
        // zero the per-step flags (graph-capture-legal, stream-ordered before lstm4)
        hipMemsetAsync((char*)d_ws + WS_FLAGS_OFF, 0, STEPS * sizeof(unsigned), stream);
        hipLaunchKernelGGL(lstm4_kernel, dim3(NBLK), dim3(1024), 0, stream,
                           inp, embed, w_ih, w_hh, b_ih, b_hh, out, d_ws);
    } else {
        hipLaunchKernelGGL(lstm_kernel, dim3(1), dim3(1024), 0, stream,
                           inp, embed, w_ih, w_hh, b_ih, b_hh, out, slots);
    }
    const int nblocks = (VOCAB + 255) / 256;   // 1954
    hipLaunchKernelGGL(vocab_kernel, dim3(nblocks), dim3(256), 0, stream,
                       embed, out, slots);
    hipLaunchKernelGGL(finalize_kernel, dim3(1), dim3(64), 0, stream,
                       slots, out + STEPS * 128);
}

// Round 6
// 524.205 us; speedup vs baseline: 1.7814x; 1.2974x over previous
//
#include <hip/hip_runtime.h>
#include <cstdint>

#define VOCAB 500000
#define STEPS 64
#define EPSF 1e-8f
#define NBLK 4
#define VGRID 1024

// ws layout: [0,512): argmax slots (u64[64]); [1024,1280): flags (u32[STEPS]);
// [4096, 4096+STEPS*NBLK*512*4): per-step per-block gate partials (step-indexed => no reuse races)
#define WS_FLAGS_OFF 1024
#define WS_PARTS_OFF 4096
#define WS_NEEDED (WS_PARTS_OFF + (size_t)STEPS * NBLK * 512 * 4)

typedef _Float16 f16x8 __attribute__((ext_vector_type(8)));
typedef float f32x16 __attribute__((ext_vector_type(16)));

__device__ __forceinline__ float sigm(float x) { return 1.f / (1.f + expf(-x)); }
__device__ __forceinline__ float dot4(float4 a, float4 b) {
    return a.x * b.x + a.y * b.y + a.z * b.z + a.w * b.w;
}
__device__ __forceinline__ unsigned long long ullmax(unsigned long long a, unsigned long long b) {
    return a > b ? a : b;
}
// order-preserving float->uint32 map (monotone increasing)
__device__ __forceinline__ unsigned fmap(float f) {
    unsigned u = __float_as_uint(f);
    return (u & 0x80000000u) ? ~u : (u | 0x80000000u);
}

// Pin a float4's lanes into VGPRs (blocks rematerialization of the defining loads).
#define PIN4(v) asm volatile("" : "+v"(v.x), "+v"(v.y), "+v"(v.z), "+v"(v.w))

// fp32 -> (f16 hi, f16 lo*2048) exact split; lo pre-scaled by 2^11 so it stays in
// f16 normal range (avoids denormal flush in the MFMA). a ~= hi + lo/2048 to 2^-22.
__device__ __forceinline__ void cvtq(float4 v, unsigned* hh, unsigned* ll) {
    _Float16 h0 = (_Float16)v.x, h1 = (_Float16)v.y, h2 = (_Float16)v.z, h3 = (_Float16)v.w;
    _Float16 e0 = (_Float16)((v.x - (float)h0) * 2048.f);
    _Float16 e1 = (_Float16)((v.y - (float)h1) * 2048.f);
    _Float16 e2 = (_Float16)((v.z - (float)h2) * 2048.f);
    _Float16 e3 = (_Float16)((v.w - (float)h3) * 2048.f);
    hh[0] = (unsigned)__builtin_bit_cast(unsigned short, h0)
          | ((unsigned)__builtin_bit_cast(unsigned short, h1) << 16);
    hh[1] = (unsigned)__builtin_bit_cast(unsigned short, h2)
          | ((unsigned)__builtin_bit_cast(unsigned short, h3) << 16);
    ll[0] = (unsigned)__builtin_bit_cast(unsigned short, e0)
          | ((unsigned)__builtin_bit_cast(unsigned short, e1) << 16);
    ll[1] = (unsigned)__builtin_bit_cast(unsigned short, e2)
          | ((unsigned)__builtin_bit_cast(unsigned short, e3) << 16);
}

// ---------------- Kernel A (v5): 4-block column-partitioned LSTM recurrence ----------------
// (unchanged from R5 — measured ~170us implied; R1-R4 showed the allocator caps this kernel's
// VGPRs, so each block holds only 8 float4 of weights = 32 VGPR, exchanged via L3 atomics)
__global__ void __launch_bounds__(1024) lstm4_kernel(
    const float* __restrict__ inp, const float* __restrict__ embed,
    const float* __restrict__ w_ih, const float* __restrict__ w_hh,
    const float* __restrict__ b_ih, const float* __restrict__ b_hh,
    float* __restrict__ out_cs,                 // d_out[0 .. 64*128)
    void* __restrict__ ws)
{
    unsigned long long* slots = (unsigned long long*)ws;
    unsigned* flags = (unsigned*)((char*)ws + WS_FLAGS_OFF);
    float* parts = (float*)((char*)ws + WS_PARTS_OFF);

    __shared__ float vv[256];         // [x(128) ; h(128)] - replicated per block
    __shared__ float part_lds[1024];  // in-block partial reduce (2 col-halves)
    __shared__ float Glds[512];       // assembled gate pre-activations
    __shared__ float kvlds[512];      // b_ih+b_hh+w_ih[:,128:256].inp

    const int t = threadIdx.x;
    const int b = blockIdx.x;
    const int r = t & 511;            // gate row
    const int ch = t >> 9;            // column half within block's slice
    const int CF0 = b * 16 + ch * 8;  // this thread's column-float4 base in v (0..63)

    if (b == 0 && t < STEPS) slots[t] = 0ull;   // vocab kernel is stream-ordered after

    const float4* wih4 = (const float4*)w_ih;   // row stride 64 float4
    const float4* whh4 = (const float4*)w_hh;   // row stride 32 float4

    // 8 float4 of weights per thread, in registers (32 VGPR pinned; fits 64-reg budget)
    float4 w[8];
#pragma unroll
    for (int j = 0; j < 8; ++j) {
        const int cf = CF0 + j;
        w[j] = (cf < 32) ? wih4[(size_t)r * 64 + cf]
                         : whh4[(size_t)r * 32 + (cf - 32)];
    }
#pragma unroll
    for (int j = 0; j < 8; ++j) PIN4(w[j]);

    // kv[r] = b_ih[r] + b_hh[r] + w_ih[r][128:256] . inp  (constant across steps)
    if (t < 512) {
        const float4* wib = wih4 + (size_t)t * 64 + 32;
        const float4* inp4 = (const float4*)inp;
        float k0 = 0.f, k1 = 0.f;
#pragma unroll 4
        for (int j = 0; j < 32; j += 2) {
            k0 += dot4(wib[j], inp4[j]);
            k1 += dot4(wib[j + 1], inp4[j + 1]);
        }
        kvlds[t] = b_ih[t] + b_hh[t] + k0 + k1;
    }
    if (t < 128) { vv[t] = embed[t]; vv[128 + t] = 0.f; }  // x0 = embed[0], h0 = 0
    float creg = 0.f;
    __syncthreads();

    const float4* vv4 = (const float4*)vv;
    for (int step = 0; step < STEPS; ++step) {
        float a = 0.f;
#pragma unroll
        for (int j = 0; j < 8; ++j) a += dot4(w[j], vv4[CF0 + j]);
        part_lds[t] = a;
        __syncthreads();

        float myp = 0.f;
        if (t < 512) {
            myp = part_lds[t] + part_lds[512 + t];
            __hip_atomic_store(&parts[((size_t)step * NBLK + b) * 512 + t], myp,
                               __ATOMIC_RELAXED, __HIP_MEMORY_SCOPE_AGENT);
        }
        __syncthreads();

        if (t == 0) {
            __hip_atomic_fetch_add(&flags[step], 1u, __ATOMIC_RELEASE,
                                   __HIP_MEMORY_SCOPE_AGENT);
            while (__hip_atomic_load(&flags[step], __ATOMIC_ACQUIRE,
                                     __HIP_MEMORY_SCOPE_AGENT) < (unsigned)NBLK) {
                __builtin_amdgcn_s_sleep(1);
            }
        }
        __syncthreads();

        if (t < 512) {
            float s = kvlds[t];
#pragma unroll
            for (int bb = 0; bb < NBLK; ++bb) {
                float p = (bb == b) ? myp
                        : __hip_atomic_load(&parts[((size_t)step * NBLK + bb) * 512 + t],
                                            __ATOMIC_RELAXED, __HIP_MEMORY_SCOPE_AGENT);
                s += p;
            }
            Glds[t] = s;
        }
        __syncthreads();

        if (t < 128) {
            float ig = sigm(Glds[t]);
            float fg = sigm(Glds[128 + t]);
            float gg = tanhf(Glds[256 + t]);
            float og = sigm(Glds[384 + t]);
            float cn = fg * creg + ig * gg;
            float hn = og * tanhf(cn);
            creg = cn;
            vv[t] = cn;            // next x = c_new
            vv[128 + t] = hn;      // next h
            if (b == 0) out_cs[step * 128 + t] = cn;
        }
        __syncthreads();
    }
}

// ---------------- Kernel A fallback (R3 version): used if ws too small ----------------
__global__ void __launch_bounds__(1024) lstm_kernel(
    const float* __restrict__ inp, const float* __restrict__ embed,
    const float* __restrict__ w_ih, const float* __restrict__ w_hh,
    const float* __restrict__ b_ih, const float* __restrict__ b_hh,
    float* __restrict__ out_cs,
    unsigned long long* __restrict__ slots)
{
    __shared__ float4 wlds4[8 * 1024];
    __shared__ float4 part4[8 * 128];
    __shared__ float vv[256];
    __shared__ float kvlds[512];

    const int t = threadIdx.x;
    const int q = t & 127;
    const int g = t >> 7;

    if (t < STEPS) slots[t] = 0ull;

    const float4* wih4 = (const float4*)w_ih;
    const float4* whh4 = (const float4*)w_hh;

    float4 wr[3][8];
#pragma unroll
    for (int k = 0; k < 3; ++k) {
        const int r = q + 128 * k;
        const float4* src = (g < 4) ? (wih4 + (size_t)r * 64 + g * 8)
                                    : (whh4 + (size_t)r * 32 + (g - 4) * 8);
#pragma unroll
        for (int j4 = 0; j4 < 8; ++j4) wr[k][j4] = src[j4];
    }
    {
        const int r = q + 384;
        const float4* src = (g < 4) ? (wih4 + (size_t)r * 64 + g * 8)
                                    : (whh4 + (size_t)r * 32 + (g - 4) * 8);
#pragma unroll
        for (int j4 = 0; j4 < 8; ++j4) wlds4[j4 * 1024 + t] = src[j4];
    }

    if (t < 512) {
        const float4* wib = wih4 + (size_t)t * 64 + 32;
        const float4* inp4 = (const float4*)inp;
        float k0 = 0.f, k1 = 0.f;
#pragma unroll 4
        for (int j = 0; j < 32; j += 2) {
            k0 += dot4(wib[j], inp4[j]);
            k1 += dot4(wib[j + 1], inp4[j + 1]);
        }
        kvlds[t] = b_ih[t] + b_hh[t] + k0 + k1;
    }

    if (t < 128) { vv[t] = embed[t]; vv[128 + t] = 0.f; }
    float creg = 0.f;
    __syncthreads();

    const float4* vv4 = (const float4*)vv;
    const int vb = g * 8;
    for (int step = 0; step < STEPS; ++step) {
        float ax = 0.f, ay = 0.f, az = 0.f, aw = 0.f;
#pragma unroll
        for (int j4 = 0; j4 < 8; ++j4) {
            float4 v  = vv4[vb + j4];
            float4 w3 = wlds4[j4 * 1024 + t];
            ax += dot4(wr[0][j4], v);
            ay += dot4(wr[1][j4], v);
            az += dot4(wr[2][j4], v);
            aw += dot4(w3, v);
        }
        part4[g * 128 + q] = make_float4(ax, ay, az, aw);
        __syncthreads();
        if (t < 128) {
            float4 s = part4[t];
#pragma unroll
            for (int g2 = 1; g2 < 8; ++g2) {
                float4 p = part4[g2 * 128 + t];
                s.x += p.x; s.y += p.y; s.z += p.z; s.w += p.w;
            }
            float ig = sigm(s.x + kvlds[t]);
            float fg = sigm(s.y + kvlds[128 + t]);
            float gg = tanhf(s.z + kvlds[256 + t]);
            float og = sigm(s.w + kvlds[384 + t]);
            float cn = fg * creg + ig * gg;
            float hn = og * tanhf(cn);
            creg = cn;
            vv[t] = cn;
            vv[128 + t] = hn;
            out_cs[step * 128 + t] = cn;
        }
        __syncthreads();
    }
}

// ---------------- Kernel B (v6): MFMA fp16-split vocab pass ----------------
// S[v,t] = E[v,:].c[t,:] via mfma_f32_32x32x16_f16 on exact fp16 splits:
//   a = hi + lo/2048 (lo stored pre-scaled ×2048; f16-normal, no denorm flush)
//   S = Hh.Hh + (Hh.Lo + Lo.Hh)/2048 + Lo.Lo/2048^2   -> error ~2^-31, argmax-safe.
// 256 thr = 4 waves: wave = (v-subtile vs 0/1) x (t-half th 0/1); 64-row tiles;
// register-prefetch -> convert -> XOR-swizzled LDS (granule ^ (row&15): conflict-free b128).
// Compute floor: MFMA ~13us/CU-total, LDS ~25us, memory 256MB -> ~41us: memory-bound.
__global__ void __launch_bounds__(256, 2) vocab_kernel(
    const float* __restrict__ embed,
    const float* __restrict__ cs,               // d_out[0..8192): [64][128] c vectors
    unsigned long long* __restrict__ slots)
{
    __shared__ unsigned Ah32[64 * 64];   // 16 KB each: [row][granule^(row&15)] packed halves
    __shared__ unsigned Al32[64 * 64];
    __shared__ unsigned Bh32[64 * 64];
    __shared__ unsigned Bl32[64 * 64];
    __shared__ float ssq[64 * 32];       // 8 KB: per-(row, c4^(row&31)) |e4|^2 partials
    __shared__ float inv_lds[64];
    __shared__ unsigned long long red[4 * 32];

    const int tid = threadIdx.x;
    const int wid = tid >> 6;
    const int l = tid & 63;
    const int lh = l >> 5;
    const int lm = l & 31;
    const int vs = wid & 1;      // v-subtile: rows [vs*32, vs*32+32)
    const int th = wid >> 1;     // t-half:   steps [th*32, th*32+32)

    // ---- stage B = c matrix (hi/lo split), once per block ----
    const float4* cs4 = (const float4*)cs;
#pragma unroll
    for (int k = 0; k < 8; ++k) {
        int f4 = tid + k * 256;
        int row = f4 >> 5, c4 = f4 & 31;
        float4 v = cs4[f4];
        unsigned hh[2], ll[2];
        cvtq(v, hh, ll);
        int u32i = (row * 16 + ((c4 >> 1) ^ (row & 15))) * 4 + (c4 & 1) * 2;
        *(unsigned long long*)&Bh32[u32i] = ((unsigned long long)hh[1] << 32) | hh[0];
        *(unsigned long long*)&Bl32[u32i] = ((unsigned long long)ll[1] << 32) | ll[0];
    }

    const float4* embed4 = (const float4*)embed;
    unsigned long long running = 0ull;
    const int stride = gridDim.x;
    const int nIter = (VOCAB + 63) >> 6;   // 7813

    // prologue prefetch (tile 'blockIdx.x')
    float4 pf[8];
    {
        const long long v0 = (long long)blockIdx.x * 64;
#pragma unroll
        for (int k = 0; k < 8; ++k) {
            int f4 = tid + k * 256;
            long long grow = v0 + (f4 >> 5);
            pf[k] = make_float4(0.f, 0.f, 0.f, 0.f);
            if (grow < VOCAB) pf[k] = embed4[grow * 32 + (f4 & 31)];
        }
    }
    __syncthreads();   // B staged

    const _Float16* AhH = (const _Float16*)Ah32;
    const _Float16* AlH = (const _Float16*)Al32;
    const _Float16* BhH = (const _Float16*)Bh32;
    const _Float16* BlH = (const _Float16*)Bl32;
    const int abase = (vs * 32 + lm) * 16, axor = (vs * 32 + lm) & 15;
    const int bbase = (th * 32 + lm) * 16, bxor = (th * 32 + lm) & 15;

    for (int it = blockIdx.x; it < nIter; it += stride) {
        const long long v0 = (long long)it * 64;

        // ---- convert prefetched tile -> A LDS + ssq partials ----
#pragma unroll
        for (int k = 0; k < 8; ++k) {
            int f4 = tid + k * 256;
            int row = f4 >> 5, c4 = f4 & 31;
            float4 v = pf[k];
            unsigned hh[2], ll[2];
            cvtq(v, hh, ll);
            int u32i = (row * 16 + ((c4 >> 1) ^ (row & 15))) * 4 + (c4 & 1) * 2;
            *(unsigned long long*)&Ah32[u32i] = ((unsigned long long)hh[1] << 32) | hh[0];
            *(unsigned long long*)&Al32[u32i] = ((unsigned long long)ll[1] << 32) | ll[0];
            ssq[row * 32 + (c4 ^ (row & 31))] = dot4(v, v);
        }
        __syncthreads();   // A tile + ssq visible; prev-iter argmax all done

        // ---- issue prefetch for next tile (lands during MFMA phase) ----
        {
            const long long v0n = (long long)(it + stride) * 64;
#pragma unroll
            for (int k = 0; k < 8; ++k) {
                int f4 = tid + k * 256;
                long long grow = v0n + (f4 >> 5);
                float4 nv = make_float4(0.f, 0.f, 0.f, 0.f);
                if (grow < VOCAB) nv = embed4[grow * 32 + (f4 & 31)];
                pf[k] = nv;
            }
        }

        // ---- per-row inverse norms (all 256 threads: row=tid>>2, quarter=tid&3) ----
        {
            int rrow = tid >> 2, quar = tid & 3;
            float s = 0.f;
#pragma unroll
            for (int j = 0; j < 8; ++j) {
                int c4 = quar * 8 + j;
                s += ssq[rrow * 32 + (c4 ^ (rrow & 31))];
            }
            s += __shfl_xor(s, 1);
            s += __shfl_xor(s, 2);
            if (quar == 0) inv_lds[rrow] = 1.f / fmaxf(sqrtf(s), EPSF);
        }

        // ---- MFMA: 4 products per K-step, 3 scaled accumulators ----
        f32x16 accm = {};
        f32x16 accx = {};
        f32x16 accl = {};
#pragma unroll
        for (int s = 0; s < 8; ++s) {
            int g = s * 2 + lh;
            int aphys = abase + (g ^ axor);
            int bphys = bbase + (g ^ bxor);
            f16x8 ah = *(const f16x8*)(AhH + aphys * 8);
            f16x8 al = *(const f16x8*)(AlH + aphys * 8);
            f16x8 bh = *(const f16x8*)(BhH + bphys * 8);
            f16x8 bl = *(const f16x8*)(BlH + bphys * 8);
            accm = __builtin_amdgcn_mfma_f32_32x32x16_f16(ah, bh, accm, 0, 0, 0);
            accx = __builtin_amdgcn_mfma_f32_32x32x16_f16(ah, bl, accx, 0, 0, 0);
            accx = __builtin_amdgcn_mfma_f32_32x32x16_f16(al, bh, accx, 0, 0, 0);
            accl = __builtin_amdgcn_mfma_f32_32x32x16_f16(al, bl, accl, 0, 0, 0);
        }
        __syncthreads();   // inv_lds ready; all A-LDS reads done (safe to restage)

        // ---- argmax update: lane covers t = th*32+lm, 16 rows via C/D mapping ----
#pragma unroll
        for (int i = 0; i < 16; ++i) {
            int rit = (i & 3) + 8 * (i >> 2) + 4 * lh + vs * 32;
            long long grow = v0 + rit;
            if (grow < VOCAB) {
                float sv = accm[i] + accx[i] * 4.8828125e-4f      // 1/2048
                                   + accl[i] * 2.384185791015625e-7f; // 1/2048^2
                float qv = sv * inv_lds[rit];
                unsigned long long key = ((unsigned long long)fmap(qv) << 32)
                                       | (unsigned)(0x7FFFFFFF - (int)grow);
                running = ullmax(running, key);
            }
        }
    }

    // ---- final reduction: lane-pair, then cross-wave via LDS ----
    running = ullmax(running, __shfl_xor(running, 32));
    if (l < 32) red[wid * 32 + l] = running;
    __syncthreads();
    if (tid < 64) {
        int t = tid, h2 = t >> 5, tc = t & 31;
        unsigned long long k = ullmax(red[(h2 * 2 + 0) * 32 + tc],
                                      red[(h2 * 2 + 1) * 32 + tc]);
        atomicMax(&slots[t], k);
    }
}

// ---------------- Kernel C: decode argmax slots to float indices ----------------
__global__ void finalize_kernel(const unsigned long long* __restrict__ slots,
                                float* __restrict__ out_dec)
{
    int t = threadIdx.x;
    if (t < STEPS) {
        unsigned idx = 0x7FFFFFFFu - (unsigned)(slots[t] & 0xFFFFFFFFu);
        out_dec[t] = (float)idx;
    }
}

extern "C" void kernel_launch(void* const* d_in, const int* in_sizes, int n_in,
                              void* d_out, int out_size, void* d_ws, size_t ws_size,
                              hipStream_t stream) {
    (void)in_sizes; (void)n_in; (void)out_size;
    const float* inp   = (const float*)d_in[0];
    const float* embed = (const float*)d_in[1];
    const float* w_ih  = (const float*)d_in[2];
    const float* w_hh  = (const float*)d_in[3];
    const float* b_ih  = (const float*)d_in[4];
    const float* b_hh  = (const float*)d_in[5];
    float* out = (float*)d_out;
    unsigned long long* slots = (unsigned long long*)d_ws;

    if (ws_size >= WS_NEEDED) {
        hipMemsetAsync((char*)d_ws + WS_FLAGS_OFF, 0, STEPS * sizeof(unsigned), stream);
        hipLaunchKernelGGL(lstm4_kernel, dim3(NBLK), dim3(1024), 0, stream,
                           inp, embed, w_ih, w_hh, b_ih, b_hh, out, d_ws);
    } else {
        hipLaunchKernelGGL(lstm_kernel, dim3(1), dim3(1024), 0, stream,
                           inp, embed, w_ih, w_hh, b_ih, b_hh, out, slots);
    }
    hipLaunchKernelGGL(vocab_kernel, dim3(VGRID), dim3(256), 0, stream,
                       embed, out, slots);
    hipLaunchKernelGGL(finalize_kernel, dim3(1), dim3(64), 0, stream,
                       slots, out + STEPS * 128);
}